// Round 3
// baseline (802.249 us; speedup 1.0000x reference)
//
#include <hip/hip_runtime.h>
#include <hip/hip_bf16.h>
#include <math.h>

#define S_LEN 4096
#define DHEAD 128
#define NHEAD 8
#define LASTQ 64
#define V_TOPK 1024
#define S_TOPK 2048
#define FORCE_V 30
#define FORCE_S 100

#define SCALE 0.08838834764831845f
#define NEGBIG -3.0e38f

typedef __attribute__((ext_vector_type(8))) short short8;
typedef __attribute__((ext_vector_type(4))) float floatx4;
typedef unsigned long long u64;

__device__ __forceinline__ unsigned short f2bf(float f) {
    unsigned u = __float_as_uint(f);
    unsigned r = (u + 0x7fffu + ((u >> 16) & 1u)) >> 16;   // RNE
    return (unsigned short)r;
}

// ---------------------------------------------------------------------------
// fp32 -> bf16 flat convert (Q and K).
// ---------------------------------------------------------------------------
__global__ __launch_bounds__(256) void cvt_bf16(const float* __restrict__ src,
                                                unsigned short* __restrict__ dst, int n4) {
    int i = blockIdx.x * 256 + threadIdx.x;
    if (i < n4) {
        float4 v = ((const float4*)src)[i];
        ushort4 o;
        o.x = f2bf(v.x); o.y = f2bf(v.y); o.z = f2bf(v.z); o.w = f2bf(v.w);
        ((ushort4*)dst)[i] = o;
    }
}

// ---------------------------------------------------------------------------
// V[h][s][d] fp32 -> Vt[h][d][s] bf16 (64x64 LDS tile transpose).
// ---------------------------------------------------------------------------
__global__ __launch_bounds__(256) void transpose_v(const float* __restrict__ v,
                                                   unsigned short* __restrict__ vt) {
    int bx = blockIdx.x;
    int h  = bx >> 7;
    int rem = bx & 127;
    int d0 = (rem >> 6) * 64;
    int k0 = (rem & 63) * 64;
    __shared__ __align__(16) unsigned short T[64][72];
    int t = threadIdx.x;
#pragma unroll
    for (int it = 0; it < 4; ++it) {
        int idx = t + it * 256;
        int r = idx >> 4, c4 = idx & 15;
        float4 val = *(const float4*)(v + ((size_t)(h * S_LEN) + k0 + r) * DHEAD + d0 + c4 * 4);
        T[c4 * 4 + 0][r] = f2bf(val.x);
        T[c4 * 4 + 1][r] = f2bf(val.y);
        T[c4 * 4 + 2][r] = f2bf(val.z);
        T[c4 * 4 + 3][r] = f2bf(val.w);
    }
    __syncthreads();
#pragma unroll
    for (int it = 0; it < 2; ++it) {
        int idx = t + it * 256;
        int r = idx >> 3, c8 = idx & 7;
        *(uint4*)(vt + ((size_t)h * DHEAD + d0 + r) * S_LEN + k0 + c8 * 8) = *(uint4*)&T[r][c8 * 8];
    }
}

// ---------------------------------------------------------------------------
// P1: scores[h][qi][j] for last-64 queries, fp32 (keeps top-k faithful).
// Each key row read once per head. 256 blocks x 128 threads.
// ---------------------------------------------------------------------------
__global__ __launch_bounds__(128) void score_qk(const float* __restrict__ q,
                                                const float* __restrict__ k,
                                                float* __restrict__ scores) {
    int h  = blockIdx.x >> 5;
    int kt = blockIdx.x & 31;
    int t  = threadIdx.x;
    int j  = kt * 128 + t;

    __shared__ float4 Qs[64 * 32];
    const float4* qbase = (const float4*)(q + ((size_t)h * S_LEN + (S_LEN - LASTQ)) * DHEAD);
    for (int idx = t; idx < 64 * 32; idx += 128) Qs[idx] = qbase[idx];
    __syncthreads();

    float4 kr[32];
    const float4* kp = (const float4*)(k + ((size_t)h * S_LEN + j) * DHEAD);
#pragma unroll
    for (int c = 0; c < 32; ++c) kr[c] = kp[c];

    float* sp = scores + (size_t)h * LASTQ * S_LEN + j;
    for (int qi = 0; qi < LASTQ; ++qi) {
        const float4* qp4 = Qs + qi * 32;
        float dot = 0.f;
#pragma unroll
        for (int c = 0; c < 32; ++c) {
            float4 a = qp4[c], b = kr[c];
            dot += a.x * b.x + a.y * b.y + a.z * b.z + a.w * b.w;
        }
        int qpos = S_LEN - LASTQ + qi;
        sp[(size_t)qi * S_LEN] = (j <= qpos) ? dot * SCALE : NEGBIG;
    }
}

// ---------------------------------------------------------------------------
// P2: per-head softmax over score rows + vertical/slash accumulation.
// 8 blocks x 1024 threads; LDS atomics for slash, no global atomics.
// ---------------------------------------------------------------------------
__global__ __launch_bounds__(1024) void pattern_reduce(const float* __restrict__ scores,
                                                       float* __restrict__ vertical,
                                                       float* __restrict__ slash) {
    int h = blockIdx.x;
    int t = threadIdx.x;
    __shared__ float sm[LASTQ], sinv[LASTQ];
    __shared__ float sl[S_LEN];
    for (int i = t; i < S_LEN; i += 1024) sl[i] = 0.f;

    int row = t >> 4, ln = t & 15;
    const float4* rp = (const float4*)(scores + ((size_t)h * LASTQ + row) * S_LEN);
    float mx = NEGBIG;
    for (int i = ln; i < S_LEN / 4; i += 16) {
        float4 s4 = rp[i];
        mx = fmaxf(mx, fmaxf(fmaxf(s4.x, s4.y), fmaxf(s4.z, s4.w)));
    }
#pragma unroll
    for (int d = 8; d >= 1; d >>= 1) mx = fmaxf(mx, __shfl_xor(mx, d, 64));
    float su = 0.f;
    for (int i = ln; i < S_LEN / 4; i += 16) {
        float4 s4 = rp[i];
        su += __expf(s4.x - mx) + __expf(s4.y - mx) + __expf(s4.z - mx) + __expf(s4.w - mx);
    }
#pragma unroll
    for (int d = 8; d >= 1; d >>= 1) su += __shfl_xor(su, d, 64);
    if (ln == 0) { sm[row] = mx; sinv[row] = 1.0f / su; }
    __syncthreads();

    for (int w = 0; w < 4; ++w) {
        int j = t + w * 1024;
        float acc = 0.f;
        for (int r = 0; r < LASTQ; ++r) {
            float s = scores[((size_t)h * LASTQ + r) * S_LEN + j];
            float p = __expf(s - sm[r]) * sinv[r];
            acc += p;
            int qpos = S_LEN - LASTQ + r;
            if (j <= qpos) atomicAdd(&sl[qpos - j], p);
        }
        vertical[h * S_LEN + j] = acc;
    }
    __syncthreads();
    for (int i = t; i < S_LEN; i += 1024) slash[h * S_LEN + i] = sl[i];
}

// ---------------------------------------------------------------------------
// Phase B: exact k-th-largest (radix select) -> membership bitmasks.
// ---------------------------------------------------------------------------
__global__ __launch_bounds__(256) void topk_mask(const float* __restrict__ vertical,
                                                 const float* __restrict__ slash,
                                                 unsigned* __restrict__ col_mask,
                                                 unsigned* __restrict__ diag_mask) {
    int h   = blockIdx.x >> 1;
    int sel = blockIdx.x & 1;
    const float* src = sel ? (slash + h * S_LEN) : (vertical + h * S_LEN);
    unsigned* dst    = sel ? (diag_mask + h * (S_LEN / 32)) : (col_mask + h * (S_LEN / 32));
    int kwant  = sel ? S_TOPK : V_TOPK;
    int forced = sel ? FORCE_S : FORCE_V;
    int t = threadIdx.x;

    __shared__ unsigned keys[S_LEN];
    __shared__ int hist[256];
    __shared__ int sh_digit, sh_want;

    for (int j = t; j < S_LEN; j += 256) {
        float f = (j < forced) ? __builtin_inff() : src[j];
        unsigned u = __float_as_uint(f);
        u = (u & 0x80000000u) ? ~u : (u | 0x80000000u);
        keys[j] = u;
    }
    __syncthreads();

    unsigned prefix = 0;
    int want = kwant;
    for (int shift = 24; shift >= 0; shift -= 8) {
        hist[t] = 0;
        __syncthreads();
        for (int j = t; j < S_LEN; j += 256) {
            unsigned key = keys[j];
            bool match = (shift == 24) || (((key ^ prefix) >> (shift + 8)) == 0);
            if (match) atomicAdd(&hist[(key >> shift) & 255u], 1);
        }
        __syncthreads();
        if (t == 0) {
            int cum = 0, d = 255;
            for (; d >= 0; --d) {
                cum += hist[d];
                if (cum >= want) break;
            }
            sh_digit = d;
            sh_want  = want - (cum - hist[d]);
        }
        __syncthreads();
        prefix |= ((unsigned)sh_digit) << shift;
        want = sh_want;
        __syncthreads();
    }
    for (int w = t; w < S_LEN / 32; w += 256) {
        unsigned bits = 0;
        for (int b = 0; b < 32; ++b)
            if (keys[w * 32 + b] >= prefix) bits |= (1u << b);
        dst[w] = bits;
    }
}

// ---------------------------------------------------------------------------
// Phase C: MFMA flash attention, split-K balanced jobs + reg prefetch.
// 768 blocks (96 jobs/head x 8 heads), 256 threads, partial (O,m,l) out.
// ---------------------------------------------------------------------------
#define KS_STRIDE 136
#define VT_STRIDE 72
#define PS_STRIDE 72

__global__ __launch_bounds__(256, 3) void sparse_attn_mfma(
        const unsigned short* __restrict__ qbf,
        const unsigned short* __restrict__ kbf,
        const unsigned short* __restrict__ vtbf,
        const unsigned* __restrict__ col_mask,
        const unsigned* __restrict__ diag_mask,
        float* __restrict__ pO, float* __restrict__ pm, float* __restrict__ pl) {
    int b = blockIdx.x;
    int h = b & 7;
    int j = b >> 3;          // 0..95, roughly descending work
    int qt, c0g, c1g, cidx;
    if (j < 64) {            // split jobs for qt in [32,63]
        qt = 63 - (j >> 1);
        int half = j & 1;
        int mid = (qt + 2) >> 1;
        cidx = half;
        c0g = half ? mid : 0;
        c1g = half ? (qt + 1) : mid;
    } else {                 // single jobs for qt in [0,31]
        qt = 95 - j;
        cidx = 0;
        c0g = 0;
        c1g = qt + 1;
    }
    int i0 = qt * 64;
    int t    = threadIdx.x;
    int wave = t >> 6;
    int lane = t & 63;
    int ln16 = lane & 15;
    int quad = lane >> 4;

    __shared__ __align__(16) unsigned short Ks[64 * KS_STRIDE];
    __shared__ __align__(16) unsigned short Vt[128 * VT_STRIDE];
    __shared__ __align__(16) unsigned short Ps[4 * 16 * PS_STRIDE];
    __shared__ u64 allowed[64];
    __shared__ unsigned dmLDS[130];

    if (t < 130) dmLDS[t] = (t < 128) ? diag_mask[h * 128 + t] : 0u;

    int qrow = i0 + wave * 16 + ln16;
    const unsigned short* qp = qbf + ((size_t)h * S_LEN + qrow) * DHEAD;
    short8 qf[4];
#pragma unroll
    for (int ds = 0; ds < 4; ++ds)
        qf[ds] = *(const short8*)(qp + ds * 32 + quad * 8);

    floatx4 o4[8];
#pragma unroll
    for (int n = 0; n < 8; ++n) o4[n] = (floatx4){0.f, 0.f, 0.f, 0.f};
    float m_run[4] = {NEGBIG, NEGBIG, NEGBIG, NEGBIG};
    float l_run[4] = {0.f, 0.f, 0.f, 0.f};

    unsigned short* psw = Ps + wave * 16 * PS_STRIDE;

    // ---- register prefetch of first tile ----
    uint4 kr[4], vr[4];
    {
        int j0 = c0g * 64;
#pragma unroll
        for (int it = 0; it < 4; ++it) {
            int idx = t + it * 256;
            int r = idx >> 4, c8 = idx & 15;
            kr[it] = *(const uint4*)(kbf + ((size_t)(h * S_LEN) + j0 + r) * DHEAD + c8 * 8);
        }
#pragma unroll
        for (int it = 0; it < 4; ++it) {
            int idx = t + it * 256;
            int r = idx >> 3, c8 = idx & 7;
            vr[it] = *(const uint4*)(vtbf + ((size_t)h * DHEAD + r) * S_LEN + j0 + c8 * 8);
        }
    }

    for (int jt = c0g; jt < c1g; ++jt) {
        int j0 = jt * 64;
        __syncthreads();   // previous tile's LDS reads done

        // ---- store prefetched regs to LDS ----
#pragma unroll
        for (int it = 0; it < 4; ++it) {
            int idx = t + it * 256;
            int r = idx >> 4, c8 = idx & 15;
            *(uint4*)&Ks[r * KS_STRIDE + c8 * 8] = kr[it];
        }
#pragma unroll
        for (int it = 0; it < 4; ++it) {
            int idx = t + it * 256;
            int r = idx >> 3, c8 = idx & 7;
            *(uint4*)&Vt[r * VT_STRIDE + c8 * 8] = vr[it];
        }
        // ---- per-row allowed bitmask ----
        if (t < 64) {
            int i = i0 + t;
            int off0 = i - j0;                       // >= 0
            u64 causal = (off0 >= 63) ? ~0ull : ((1ull << (off0 + 1)) - 1ull);
            u64 cwv = ((u64)col_mask[h * 128 + (j0 >> 5) + 1] << 32) |
                      (u64)col_mask[h * 128 + (j0 >> 5)];
            int sb = off0 - 63;
            u64 V;
            if (sb >= 0) {
                int w = sb >> 5, sh = sb & 31;
                u64 lo = ((u64)dmLDS[w + 1] << 32) | (u64)dmLDS[w];
                u64 hi = (u64)dmLDS[w + 2];
                V = (lo >> sh) | (sh ? (hi << (64 - sh)) : 0ull);
            } else {
                u64 w0 = ((u64)dmLDS[1] << 32) | (u64)dmLDS[0];
                V = w0 << (-sb);
            }
            allowed[t] = (cwv | __brevll(V)) & causal;
        }
        __syncthreads();

        // ---- prefetch next tile into regs (overlaps with compute) ----
        if (jt + 1 < c1g) {
            int jn = j0 + 64;
#pragma unroll
            for (int it = 0; it < 4; ++it) {
                int idx = t + it * 256;
                int r = idx >> 4, c8 = idx & 15;
                kr[it] = *(const uint4*)(kbf + ((size_t)(h * S_LEN) + jn + r) * DHEAD + c8 * 8);
            }
#pragma unroll
            for (int it = 0; it < 4; ++it) {
                int idx = t + it * 256;
                int r = idx >> 3, c8 = idx & 7;
                vr[it] = *(const uint4*)(vtbf + ((size_t)h * DHEAD + r) * S_LEN + jn + c8 * 8);
            }
        }

        // ---- S = Q K^T ----
        floatx4 s_acc[4];
#pragma unroll
        for (int c = 0; c < 4; ++c) {
            s_acc[c] = (floatx4){0.f, 0.f, 0.f, 0.f};
            const unsigned short* kbase = Ks + (c * 16 + ln16) * KS_STRIDE + quad * 8;
#pragma unroll
            for (int ds = 0; ds < 4; ++ds) {
                short8 kf = *(const short8*)(kbase + ds * 32);
                s_acc[c] = __builtin_amdgcn_mfma_f32_16x16x32_bf16(qf[ds], kf, s_acc[c], 0, 0, 0);
            }
        }

        // ---- mask + scale ----
        u64 Arow[4];
#pragma unroll
        for (int r = 0; r < 4; ++r)
            Arow[r] = allowed[wave * 16 + quad * 4 + r];
        float sc[4][4];
#pragma unroll
        for (int c = 0; c < 4; ++c)
#pragma unroll
            for (int r = 0; r < 4; ++r) {
                bool ok = (Arow[r] >> (c * 16 + ln16)) & 1ull;
                sc[c][r] = ok ? s_acc[c][r] * SCALE : -__builtin_inff();
            }

        // ---- online softmax ----
        float mnew[4], alpha[4];
#pragma unroll
        for (int r = 0; r < 4; ++r) {
            float mx = fmaxf(fmaxf(sc[0][r], sc[1][r]), fmaxf(sc[2][r], sc[3][r]));
#pragma unroll
            for (int d = 8; d >= 1; d >>= 1) mx = fmaxf(mx, __shfl_xor(mx, d, 64));
            mnew[r] = fmaxf(m_run[r], mx);
            alpha[r] = __expf(m_run[r] - mnew[r]);
            m_run[r] = mnew[r];
        }
        float pv[4][4];
#pragma unroll
        for (int r = 0; r < 4; ++r) {
            float su = 0.f;
#pragma unroll
            for (int c = 0; c < 4; ++c) {
                float p = __expf(sc[c][r] - mnew[r]);
                pv[c][r] = p;
                su += p;
            }
#pragma unroll
            for (int d = 8; d >= 1; d >>= 1) su += __shfl_xor(su, d, 64);
            l_run[r] = l_run[r] * alpha[r] + su;
        }
#pragma unroll
        for (int n = 0; n < 8; ++n)
#pragma unroll
            for (int r = 0; r < 4; ++r) o4[n][r] *= alpha[r];

        // ---- P (C-layout) -> wave-private LDS -> A-layout ----
#pragma unroll
        for (int c = 0; c < 4; ++c)
#pragma unroll
            for (int r = 0; r < 4; ++r)
                psw[(quad * 4 + r) * PS_STRIDE + c * 16 + ln16] = f2bf(pv[c][r]);
        asm volatile("" ::: "memory");
        short8 pf0 = *(const short8*)&psw[ln16 * PS_STRIDE + quad * 8];
        short8 pf1 = *(const short8*)&psw[ln16 * PS_STRIDE + 32 + quad * 8];

        // ---- O += P V ----
#pragma unroll
        for (int n = 0; n < 8; ++n) {
            const unsigned short* vbase = Vt + (n * 16 + ln16) * VT_STRIDE + quad * 8;
            short8 vf0 = *(const short8*)(vbase);
            short8 vf1 = *(const short8*)(vbase + 32);
            o4[n] = __builtin_amdgcn_mfma_f32_16x16x32_bf16(pf0, vf0, o4[n], 0, 0, 0);
            o4[n] = __builtin_amdgcn_mfma_f32_16x16x32_bf16(pf1, vf1, o4[n], 0, 0, 0);
        }
    }

    // ---- write partial (O, m, l) ----
    int pi = (h * 64 + qt) * 2 + cidx;
    float* pOp = pO + (size_t)pi * (64 * DHEAD);
#pragma unroll
    for (int r = 0; r < 4; ++r) {
        int row = wave * 16 + quad * 4 + r;
        if (ln16 == 0) { pm[pi * 64 + row] = m_run[r]; pl[pi * 64 + row] = l_run[r]; }
#pragma unroll
        for (int n = 0; n < 8; ++n)
            pOp[row * DHEAD + n * 16 + ln16] = o4[n][r];
    }
}

// ---------------------------------------------------------------------------
// Merge partials -> normalized output. 512 blocks x 256 threads.
// ---------------------------------------------------------------------------
__global__ __launch_bounds__(256) void merge_out(const float* __restrict__ pO,
                                                 const float* __restrict__ pm,
                                                 const float* __restrict__ pl,
                                                 float* __restrict__ out) {
    int b = blockIdx.x;              // h*64 + qt
    int qt = b & 63;
    int t = threadIdx.x;
    int row = t >> 2, cg = t & 3;
    int pi0 = b * 2;
    bool two = (qt >= 32);

    float m0 = pm[pi0 * 64 + row], l0 = pl[pi0 * 64 + row];
    float w0 = 1.f, w1 = 0.f, denom = l0;
    if (two) {
        float m1 = pm[(pi0 + 1) * 64 + row], l1 = pl[(pi0 + 1) * 64 + row];
        float ms = fmaxf(m0, m1);
        w0 = __expf(m0 - ms);
        w1 = __expf(m1 - ms);
        denom = w0 * l0 + w1 * l1;
    }
    float invl = 1.0f / denom;

    const float4* O0 = (const float4*)(pO + (size_t)pi0 * (64 * DHEAD) + row * DHEAD + cg * 32);
    const float4* O1 = (const float4*)((const float*)O0 + 64 * DHEAD);
    float4* op = (float4*)(out + ((size_t)b * 64 + row) * DHEAD + cg * 32);
#pragma unroll
    for (int i = 0; i < 8; ++i) {
        float4 a = O0[i];
        float4 c;
        if (two) {
            float4 bb = O1[i];
            c.x = (w0 * a.x + w1 * bb.x) * invl;
            c.y = (w0 * a.y + w1 * bb.y) * invl;
            c.z = (w0 * a.z + w1 * bb.z) * invl;
            c.w = (w0 * a.w + w1 * bb.w) * invl;
        } else {
            c.x = a.x * invl; c.y = a.y * invl; c.z = a.z * invl; c.w = a.w * invl;
        }
        op[i] = c;
    }
}

// ---------------------------------------------------------------------------
extern "C" void kernel_launch(void* const* d_in, const int* in_sizes, int n_in,
                              void* d_out, int out_size, void* d_ws, size_t ws_size,
                              hipStream_t stream) {
    const float* q = (const float*)d_in[0];
    const float* k = (const float*)d_in[1];
    const float* v = (const float*)d_in[2];
    float* out = (float*)d_out;

    float* vertical = (float*)d_ws;                              // 32768 f32
    float* slash    = vertical + NHEAD * S_LEN;                  // 32768 f32
    unsigned* col_m  = (unsigned*)(slash + NHEAD * S_LEN);       // 1024 u32
    unsigned* diag_m = col_m + NHEAD * (S_LEN / 32);             // 1024 u32
    unsigned short* qbf  = (unsigned short*)(diag_m + NHEAD * (S_LEN / 32));
    unsigned short* kbf  = qbf + (size_t)NHEAD * S_LEN * DHEAD;
    unsigned short* vtbf = kbf + (size_t)NHEAD * S_LEN * DHEAD;
    // big region: scores (8 MB) during pattern phase, pO (32 MB) during attention
    float* big = (float*)(vtbf + (size_t)NHEAD * S_LEN * DHEAD);
    float* scores = big;
    float* pO = big;
    float* pm = big + (size_t)1024 * 64 * DHEAD;                 // 65536 f32
    float* pl = pm + 1024 * 64;                                  // 65536 f32

    int n4 = NHEAD * S_LEN * DHEAD / 4;
    cvt_bf16<<<(n4 + 255) / 256, 256, 0, stream>>>(q, qbf, n4);
    cvt_bf16<<<(n4 + 255) / 256, 256, 0, stream>>>(k, kbf, n4);
    transpose_v<<<NHEAD * 2 * (S_LEN / 64), 256, 0, stream>>>(v, vtbf);

    score_qk<<<NHEAD * 32, 128, 0, stream>>>(q, k, scores);
    pattern_reduce<<<NHEAD, 1024, 0, stream>>>(scores, vertical, slash);
    topk_mask<<<NHEAD * 2, 256, 0, stream>>>(vertical, slash, col_m, diag_m);

    sparse_attn_mfma<<<NHEAD * 96, 256, 0, stream>>>(qbf, kbf, vtbf, col_m, diag_m, pO, pm, pl);
    merge_out<<<NHEAD * 64, 256, 0, stream>>>(pO, pm, pl, out);
}

// Round 4
// 463.163 us; speedup vs baseline: 1.7321x; 1.7321x over previous
//
#include <hip/hip_runtime.h>
#include <hip/hip_bf16.h>
#include <math.h>

#define S_LEN 4096
#define DHEAD 128
#define NHEAD 8
#define LASTQ 64
#define V_TOPK 1024
#define S_TOPK 2048
#define FORCE_V 30
#define FORCE_S 100

#define SCALE 0.08838834764831845f
#define NEGBIG -3.0e38f

typedef __attribute__((ext_vector_type(8))) short short8;
typedef __attribute__((ext_vector_type(4))) float floatx4;
typedef unsigned long long u64;

__device__ __forceinline__ unsigned short f2bf(float f) {
    unsigned u = __float_as_uint(f);
    unsigned r = (u + 0x7fffu + ((u >> 16) & 1u)) >> 16;   // RNE
    return (unsigned short)r;
}

// ---------------------------------------------------------------------------
// fp32 -> bf16 flat convert (Q and K).
// ---------------------------------------------------------------------------
__global__ __launch_bounds__(256) void cvt_bf16(const float* __restrict__ src,
                                                unsigned short* __restrict__ dst, int n4) {
    int i = blockIdx.x * 256 + threadIdx.x;
    if (i < n4) {
        float4 v = ((const float4*)src)[i];
        ushort4 o;
        o.x = f2bf(v.x); o.y = f2bf(v.y); o.z = f2bf(v.z); o.w = f2bf(v.w);
        ((ushort4*)dst)[i] = o;
    }
}

// ---------------------------------------------------------------------------
// V[h][s][d] fp32 -> Vt[h][d][s] bf16 (64x64 LDS tile transpose).
// ---------------------------------------------------------------------------
__global__ __launch_bounds__(256) void transpose_v(const float* __restrict__ v,
                                                   unsigned short* __restrict__ vt) {
    int bx = blockIdx.x;
    int h  = bx >> 7;
    int rem = bx & 127;
    int d0 = (rem >> 6) * 64;
    int k0 = (rem & 63) * 64;
    __shared__ __align__(16) unsigned short T[64][72];
    int t = threadIdx.x;
#pragma unroll
    for (int it = 0; it < 4; ++it) {
        int idx = t + it * 256;
        int r = idx >> 4, c4 = idx & 15;
        float4 val = *(const float4*)(v + ((size_t)(h * S_LEN) + k0 + r) * DHEAD + d0 + c4 * 4);
        T[c4 * 4 + 0][r] = f2bf(val.x);
        T[c4 * 4 + 1][r] = f2bf(val.y);
        T[c4 * 4 + 2][r] = f2bf(val.z);
        T[c4 * 4 + 3][r] = f2bf(val.w);
    }
    __syncthreads();
#pragma unroll
    for (int it = 0; it < 2; ++it) {
        int idx = t + it * 256;
        int r = idx >> 3, c8 = idx & 7;
        *(uint4*)(vt + ((size_t)h * DHEAD + d0 + r) * S_LEN + k0 + c8 * 8) = *(uint4*)&T[r][c8 * 8];
    }
}

// ---------------------------------------------------------------------------
// P1: scores[h][qi][j] for last-64 queries, fp32 (keeps top-k faithful).
// 512 blocks x 256 threads; 4 lanes cooperate per key (32 dims each).
// ---------------------------------------------------------------------------
__global__ __launch_bounds__(256) void score_qk(const float* __restrict__ q,
                                                const float* __restrict__ k,
                                                float* __restrict__ scores) {
    int h  = blockIdx.x >> 6;
    int kt = blockIdx.x & 63;
    int t  = threadIdx.x;
    int jl = t >> 2, part = t & 3;
    int j  = kt * 64 + jl;

    __shared__ float4 Qs[64 * 32];
    const float4* qbase = (const float4*)(q + ((size_t)h * S_LEN + (S_LEN - LASTQ)) * DHEAD);
    for (int idx = t; idx < 64 * 32; idx += 256) Qs[idx] = qbase[idx];
    __syncthreads();

    float4 kr[8];
    const float4* kp = (const float4*)(k + ((size_t)h * S_LEN + j) * DHEAD) + part * 8;
#pragma unroll
    for (int c = 0; c < 8; ++c) kr[c] = kp[c];

    float* sp = scores + (size_t)h * LASTQ * S_LEN + j;
#pragma unroll 4
    for (int qi = 0; qi < LASTQ; ++qi) {
        const float4* qp4 = Qs + qi * 32 + part * 8;
        float dot = 0.f;
#pragma unroll
        for (int c = 0; c < 8; ++c) {
            float4 a = qp4[c], b = kr[c];
            dot += a.x * b.x + a.y * b.y + a.z * b.z + a.w * b.w;
        }
        dot += __shfl_xor(dot, 1, 64);
        dot += __shfl_xor(dot, 2, 64);
        if (part == 0) {
            int qpos = S_LEN - LASTQ + qi;
            sp[(size_t)qi * S_LEN] = (j <= qpos) ? dot * SCALE : NEGBIG;
        }
    }
}

// ---------------------------------------------------------------------------
// P2a: per-row softmax stats (m, 1/sum). 512 rows, one wave per row.
// ---------------------------------------------------------------------------
__global__ __launch_bounds__(256) void row_stats(const float* __restrict__ scores,
                                                 float* __restrict__ m_out,
                                                 float* __restrict__ inv_out) {
    int row  = blockIdx.x * 4 + (threadIdx.x >> 6);   // 128 blocks
    int lane = threadIdx.x & 63;
    const float4* rp = (const float4*)(scores + (size_t)row * S_LEN);
    float mx = NEGBIG;
    for (int i = lane; i < S_LEN / 4; i += 64) {
        float4 s4 = rp[i];
        mx = fmaxf(mx, fmaxf(fmaxf(s4.x, s4.y), fmaxf(s4.z, s4.w)));
    }
#pragma unroll
    for (int d = 32; d >= 1; d >>= 1) mx = fmaxf(mx, __shfl_xor(mx, d, 64));
    float su = 0.f;
    for (int i = lane; i < S_LEN / 4; i += 64) {
        float4 s4 = rp[i];
        su += __expf(s4.x - mx) + __expf(s4.y - mx) + __expf(s4.z - mx) + __expf(s4.w - mx);
    }
#pragma unroll
    for (int d = 32; d >= 1; d >>= 1) su += __shfl_xor(su, d, 64);
    if (lane == 0) { m_out[row] = mx; inv_out[row] = 1.0f / su; }
}

// ---------------------------------------------------------------------------
// P2b: vertical[j] and slash[o] directly (no atomics, coalesced gathers).
// 64 blocks x 256 threads.
// ---------------------------------------------------------------------------
__global__ __launch_bounds__(256) void vs_accum(const float* __restrict__ scores,
                                                const float* __restrict__ m_all,
                                                const float* __restrict__ inv_all,
                                                float* __restrict__ vertical,
                                                float* __restrict__ slash) {
    int h     = blockIdx.x >> 3;
    int chunk = blockIdx.x & 7;
    int t = threadIdx.x;
    __shared__ float sm[LASTQ], sv[LASTQ];
    if (t < LASTQ) { sm[t] = m_all[h * LASTQ + t]; sv[t] = inv_all[h * LASTQ + t]; }
    __syncthreads();

    const float* S0 = scores + (size_t)h * LASTQ * S_LEN;
#pragma unroll
    for (int rep = 0; rep < 2; ++rep) {
        int j = chunk * 512 + rep * 256 + t;
        float vacc = 0.f, sacc = 0.f;
        for (int r = 0; r < LASTQ; ++r) {
            // vertical: masked entries hold NEGBIG -> exp underflows to 0
            vacc += __expf(S0[(size_t)r * S_LEN + j] - sm[r]) * sv[r];
            int idx = (S_LEN - LASTQ) + r - j;        // qpos_r - offset
            if (idx >= 0)
                sacc += __expf(S0[(size_t)r * S_LEN + idx] - sm[r]) * sv[r];
        }
        vertical[h * S_LEN + j] = vacc;
        slash[h * S_LEN + j]    = sacc;
    }
}

// ---------------------------------------------------------------------------
// Phase B: exact k-th-largest (radix select) -> membership bitmasks.
// ---------------------------------------------------------------------------
__global__ __launch_bounds__(256) void topk_mask(const float* __restrict__ vertical,
                                                 const float* __restrict__ slash,
                                                 unsigned* __restrict__ col_mask,
                                                 unsigned* __restrict__ diag_mask) {
    int h   = blockIdx.x >> 1;
    int sel = blockIdx.x & 1;
    const float* src = sel ? (slash + h * S_LEN) : (vertical + h * S_LEN);
    unsigned* dst    = sel ? (diag_mask + h * (S_LEN / 32)) : (col_mask + h * (S_LEN / 32));
    int kwant  = sel ? S_TOPK : V_TOPK;
    int forced = sel ? FORCE_S : FORCE_V;
    int t = threadIdx.x;

    __shared__ unsigned keys[S_LEN];
    __shared__ int hist[256];
    __shared__ int sh_digit, sh_want;

    for (int j = t; j < S_LEN; j += 256) {
        float f = (j < forced) ? __builtin_inff() : src[j];
        unsigned u = __float_as_uint(f);
        u = (u & 0x80000000u) ? ~u : (u | 0x80000000u);
        keys[j] = u;
    }
    __syncthreads();

    unsigned prefix = 0;
    int want = kwant;
    for (int shift = 24; shift >= 0; shift -= 8) {
        hist[t] = 0;
        __syncthreads();
        for (int j = t; j < S_LEN; j += 256) {
            unsigned key = keys[j];
            bool match = (shift == 24) || (((key ^ prefix) >> (shift + 8)) == 0);
            if (match) atomicAdd(&hist[(key >> shift) & 255u], 1);
        }
        __syncthreads();
        if (t == 0) {
            int cum = 0, d = 255;
            for (; d >= 0; --d) {
                cum += hist[d];
                if (cum >= want) break;
            }
            sh_digit = d;
            sh_want  = want - (cum - hist[d]);
        }
        __syncthreads();
        prefix |= ((unsigned)sh_digit) << shift;
        want = sh_want;
        __syncthreads();
    }
    for (int w = t; w < S_LEN / 32; w += 256) {
        unsigned bits = 0;
        for (int b = 0; b < 32; ++b)
            if (keys[w * 32 + b] >= prefix) bits |= (1u << b);
        dst[w] = bits;
    }
}

// ---------------------------------------------------------------------------
// Phase C: MFMA flash attention, split-K balanced jobs + reg prefetch.
// ---------------------------------------------------------------------------
#define KS_STRIDE 136
#define VT_STRIDE 72
#define PS_STRIDE 72

__global__ __launch_bounds__(256, 3) void sparse_attn_mfma(
        const unsigned short* __restrict__ qbf,
        const unsigned short* __restrict__ kbf,
        const unsigned short* __restrict__ vtbf,
        const unsigned* __restrict__ col_mask,
        const unsigned* __restrict__ diag_mask,
        float* __restrict__ pO, float* __restrict__ pm, float* __restrict__ pl) {
    int b = blockIdx.x;
    int h = b & 7;
    int j = b >> 3;          // 0..95, roughly descending work
    int qt, c0g, c1g, cidx;
    if (j < 64) {            // split jobs for qt in [32,63]
        qt = 63 - (j >> 1);
        int half = j & 1;
        int mid = (qt + 2) >> 1;
        cidx = half;
        c0g = half ? mid : 0;
        c1g = half ? (qt + 1) : mid;
    } else {                 // single jobs for qt in [0,31]
        qt = 95 - j;
        cidx = 0;
        c0g = 0;
        c1g = qt + 1;
    }
    int i0 = qt * 64;
    int t    = threadIdx.x;
    int wave = t >> 6;
    int lane = t & 63;
    int ln16 = lane & 15;
    int quad = lane >> 4;

    __shared__ __align__(16) unsigned short Ks[64 * KS_STRIDE];
    __shared__ __align__(16) unsigned short Vt[128 * VT_STRIDE];
    __shared__ __align__(16) unsigned short Ps[4 * 16 * PS_STRIDE];
    __shared__ u64 allowed[64];
    __shared__ unsigned dmLDS[130];

    if (t < 130) dmLDS[t] = (t < 128) ? diag_mask[h * 128 + t] : 0u;

    int qrow = i0 + wave * 16 + ln16;
    const unsigned short* qp = qbf + ((size_t)h * S_LEN + qrow) * DHEAD;
    short8 qf[4];
#pragma unroll
    for (int ds = 0; ds < 4; ++ds)
        qf[ds] = *(const short8*)(qp + ds * 32 + quad * 8);

    floatx4 o4[8];
#pragma unroll
    for (int n = 0; n < 8; ++n) o4[n] = (floatx4){0.f, 0.f, 0.f, 0.f};
    float m_run[4] = {NEGBIG, NEGBIG, NEGBIG, NEGBIG};
    float l_run[4] = {0.f, 0.f, 0.f, 0.f};

    unsigned short* psw = Ps + wave * 16 * PS_STRIDE;

    // ---- register prefetch of first tile ----
    uint4 kr[4], vr[4];
    {
        int j0 = c0g * 64;
#pragma unroll
        for (int it = 0; it < 4; ++it) {
            int idx = t + it * 256;
            int r = idx >> 4, c8 = idx & 15;
            kr[it] = *(const uint4*)(kbf + ((size_t)(h * S_LEN) + j0 + r) * DHEAD + c8 * 8);
        }
#pragma unroll
        for (int it = 0; it < 4; ++it) {
            int idx = t + it * 256;
            int r = idx >> 3, c8 = idx & 7;
            vr[it] = *(const uint4*)(vtbf + ((size_t)h * DHEAD + r) * S_LEN + j0 + c8 * 8);
        }
    }

    for (int jt = c0g; jt < c1g; ++jt) {
        int j0 = jt * 64;
        __syncthreads();   // previous tile's LDS reads done

#pragma unroll
        for (int it = 0; it < 4; ++it) {
            int idx = t + it * 256;
            int r = idx >> 4, c8 = idx & 15;
            *(uint4*)&Ks[r * KS_STRIDE + c8 * 8] = kr[it];
        }
#pragma unroll
        for (int it = 0; it < 4; ++it) {
            int idx = t + it * 256;
            int r = idx >> 3, c8 = idx & 7;
            *(uint4*)&Vt[r * VT_STRIDE + c8 * 8] = vr[it];
        }
        if (t < 64) {
            int i = i0 + t;
            int off0 = i - j0;
            u64 causal = (off0 >= 63) ? ~0ull : ((1ull << (off0 + 1)) - 1ull);
            u64 cwv = ((u64)col_mask[h * 128 + (j0 >> 5) + 1] << 32) |
                      (u64)col_mask[h * 128 + (j0 >> 5)];
            int sb = off0 - 63;
            u64 V;
            if (sb >= 0) {
                int w = sb >> 5, sh = sb & 31;
                u64 lo = ((u64)dmLDS[w + 1] << 32) | (u64)dmLDS[w];
                u64 hi = (u64)dmLDS[w + 2];
                V = (lo >> sh) | (sh ? (hi << (64 - sh)) : 0ull);
            } else {
                u64 w0 = ((u64)dmLDS[1] << 32) | (u64)dmLDS[0];
                V = w0 << (-sb);
            }
            allowed[t] = (cwv | __brevll(V)) & causal;
        }
        __syncthreads();

        if (jt + 1 < c1g) {
            int jn = j0 + 64;
#pragma unroll
            for (int it = 0; it < 4; ++it) {
                int idx = t + it * 256;
                int r = idx >> 4, c8 = idx & 15;
                kr[it] = *(const uint4*)(kbf + ((size_t)(h * S_LEN) + jn + r) * DHEAD + c8 * 8);
            }
#pragma unroll
            for (int it = 0; it < 4; ++it) {
                int idx = t + it * 256;
                int r = idx >> 3, c8 = idx & 7;
                vr[it] = *(const uint4*)(vtbf + ((size_t)h * DHEAD + r) * S_LEN + jn + c8 * 8);
            }
        }

        floatx4 s_acc[4];
#pragma unroll
        for (int c = 0; c < 4; ++c) {
            s_acc[c] = (floatx4){0.f, 0.f, 0.f, 0.f};
            const unsigned short* kbase = Ks + (c * 16 + ln16) * KS_STRIDE + quad * 8;
#pragma unroll
            for (int ds = 0; ds < 4; ++ds) {
                short8 kf = *(const short8*)(kbase + ds * 32);
                s_acc[c] = __builtin_amdgcn_mfma_f32_16x16x32_bf16(qf[ds], kf, s_acc[c], 0, 0, 0);
            }
        }

        u64 Arow[4];
#pragma unroll
        for (int r = 0; r < 4; ++r)
            Arow[r] = allowed[wave * 16 + quad * 4 + r];
        float sc[4][4];
#pragma unroll
        for (int c = 0; c < 4; ++c)
#pragma unroll
            for (int r = 0; r < 4; ++r) {
                bool ok = (Arow[r] >> (c * 16 + ln16)) & 1ull;
                sc[c][r] = ok ? s_acc[c][r] * SCALE : -__builtin_inff();
            }

        float mnew[4], alpha[4];
#pragma unroll
        for (int r = 0; r < 4; ++r) {
            float mx = fmaxf(fmaxf(sc[0][r], sc[1][r]), fmaxf(sc[2][r], sc[3][r]));
#pragma unroll
            for (int d = 8; d >= 1; d >>= 1) mx = fmaxf(mx, __shfl_xor(mx, d, 64));
            mnew[r] = fmaxf(m_run[r], mx);
            alpha[r] = __expf(m_run[r] - mnew[r]);
            m_run[r] = mnew[r];
        }
        float pv[4][4];
#pragma unroll
        for (int r = 0; r < 4; ++r) {
            float su = 0.f;
#pragma unroll
            for (int c = 0; c < 4; ++c) {
                float p = __expf(sc[c][r] - mnew[r]);
                pv[c][r] = p;
                su += p;
            }
#pragma unroll
            for (int d = 8; d >= 1; d >>= 1) su += __shfl_xor(su, d, 64);
            l_run[r] = l_run[r] * alpha[r] + su;
        }
#pragma unroll
        for (int n = 0; n < 8; ++n)
#pragma unroll
            for (int r = 0; r < 4; ++r) o4[n][r] *= alpha[r];

#pragma unroll
        for (int c = 0; c < 4; ++c)
#pragma unroll
            for (int r = 0; r < 4; ++r)
                psw[(quad * 4 + r) * PS_STRIDE + c * 16 + ln16] = f2bf(pv[c][r]);
        asm volatile("" ::: "memory");
        short8 pf0 = *(const short8*)&psw[ln16 * PS_STRIDE + quad * 8];
        short8 pf1 = *(const short8*)&psw[ln16 * PS_STRIDE + 32 + quad * 8];

#pragma unroll
        for (int n = 0; n < 8; ++n) {
            const unsigned short* vbase = Vt + (n * 16 + ln16) * VT_STRIDE + quad * 8;
            short8 vf0 = *(const short8*)(vbase);
            short8 vf1 = *(const short8*)(vbase + 32);
            o4[n] = __builtin_amdgcn_mfma_f32_16x16x32_bf16(pf0, vf0, o4[n], 0, 0, 0);
            o4[n] = __builtin_amdgcn_mfma_f32_16x16x32_bf16(pf1, vf1, o4[n], 0, 0, 0);
        }
    }

    int pi = (h * 64 + qt) * 2 + cidx;
    float* pOp = pO + (size_t)pi * (64 * DHEAD);
#pragma unroll
    for (int r = 0; r < 4; ++r) {
        int row = wave * 16 + quad * 4 + r;
        if (ln16 == 0) { pm[pi * 64 + row] = m_run[r]; pl[pi * 64 + row] = l_run[r]; }
#pragma unroll
        for (int n = 0; n < 8; ++n)
            pOp[row * DHEAD + n * 16 + ln16] = o4[n][r];
    }
}

// ---------------------------------------------------------------------------
// Merge partials -> normalized output. 512 blocks x 256 threads.
// ---------------------------------------------------------------------------
__global__ __launch_bounds__(256) void merge_out(const float* __restrict__ pO,
                                                 const float* __restrict__ pm,
                                                 const float* __restrict__ pl,
                                                 float* __restrict__ out) {
    int b = blockIdx.x;
    int qt = b & 63;
    int t = threadIdx.x;
    int row = t >> 2, cg = t & 3;
    int pi0 = b * 2;
    bool two = (qt >= 32);

    float m0 = pm[pi0 * 64 + row], l0 = pl[pi0 * 64 + row];
    float w0 = 1.f, w1 = 0.f, denom = l0;
    if (two) {
        float m1 = pm[(pi0 + 1) * 64 + row], l1 = pl[(pi0 + 1) * 64 + row];
        float ms = fmaxf(m0, m1);
        w0 = __expf(m0 - ms);
        w1 = __expf(m1 - ms);
        denom = w0 * l0 + w1 * l1;
    }
    float invl = 1.0f / denom;

    const float4* O0 = (const float4*)(pO + (size_t)pi0 * (64 * DHEAD) + row * DHEAD + cg * 32);
    const float4* O1 = (const float4*)((const float*)O0 + 64 * DHEAD);
    float4* op = (float4*)(out + ((size_t)b * 64 + row) * DHEAD + cg * 32);
#pragma unroll
    for (int i = 0; i < 8; ++i) {
        float4 a = O0[i];
        float4 c;
        if (two) {
            float4 bb = O1[i];
            c.x = (w0 * a.x + w1 * bb.x) * invl;
            c.y = (w0 * a.y + w1 * bb.y) * invl;
            c.z = (w0 * a.z + w1 * bb.z) * invl;
            c.w = (w0 * a.w + w1 * bb.w) * invl;
        } else {
            c.x = a.x * invl; c.y = a.y * invl; c.z = a.z * invl; c.w = a.w * invl;
        }
        op[i] = c;
    }
}

// ---------------------------------------------------------------------------
extern "C" void kernel_launch(void* const* d_in, const int* in_sizes, int n_in,
                              void* d_out, int out_size, void* d_ws, size_t ws_size,
                              hipStream_t stream) {
    const float* q = (const float*)d_in[0];
    const float* k = (const float*)d_in[1];
    const float* v = (const float*)d_in[2];
    float* out = (float*)d_out;

    float* vertical = (float*)d_ws;                              // 32768 f32
    float* slash    = vertical + NHEAD * S_LEN;                  // 32768 f32
    unsigned* col_m  = (unsigned*)(slash + NHEAD * S_LEN);       // 1024 u32
    unsigned* diag_m = col_m + NHEAD * (S_LEN / 32);             // 1024 u32
    float* m_all   = (float*)(diag_m + NHEAD * (S_LEN / 32));    // 512 f32
    float* inv_all = m_all + NHEAD * LASTQ;                      // 512 f32
    unsigned short* qbf  = (unsigned short*)(inv_all + NHEAD * LASTQ);
    unsigned short* kbf  = qbf + (size_t)NHEAD * S_LEN * DHEAD;
    unsigned short* vtbf = kbf + (size_t)NHEAD * S_LEN * DHEAD;
    // big region: scores (8 MB) during pattern phase, pO (32 MB) during attention
    float* big = (float*)(vtbf + (size_t)NHEAD * S_LEN * DHEAD);
    float* scores = big;
    float* pO = big;
    float* pm = big + (size_t)1024 * 64 * DHEAD;
    float* pl = pm + 1024 * 64;

    int n4 = NHEAD * S_LEN * DHEAD / 4;
    cvt_bf16<<<(n4 + 255) / 256, 256, 0, stream>>>(q, qbf, n4);
    cvt_bf16<<<(n4 + 255) / 256, 256, 0, stream>>>(k, kbf, n4);
    transpose_v<<<NHEAD * 2 * (S_LEN / 64), 256, 0, stream>>>(v, vtbf);

    score_qk<<<NHEAD * 64, 256, 0, stream>>>(q, k, scores);
    row_stats<<<NHEAD * LASTQ / 4, 256, 0, stream>>>(scores, m_all, inv_all);
    vs_accum<<<NHEAD * 8, 256, 0, stream>>>(scores, m_all, inv_all, vertical, slash);
    topk_mask<<<NHEAD * 2, 256, 0, stream>>>(vertical, slash, col_m, diag_m);

    sparse_attn_mfma<<<NHEAD * 96, 256, 0, stream>>>(qbf, kbf, vtbf, col_m, diag_m, pO, pm, pl);
    merge_out<<<NHEAD * 64, 256, 0, stream>>>(pO, pm, pl, out);
}

// Round 5
// 362.232 us; speedup vs baseline: 2.2147x; 1.2786x over previous
//
#include <hip/hip_runtime.h>
#include <hip/hip_bf16.h>
#include <math.h>

#define S_LEN 4096
#define DHEAD 128
#define NHEAD 8
#define LASTQ 64
#define V_TOPK 1024
#define S_TOPK 2048
#define FORCE_V 30
#define FORCE_S 100

#define SCALE 0.08838834764831845f
#define NEGBIG -3.0e38f

typedef __attribute__((ext_vector_type(8))) short short8;
typedef __attribute__((ext_vector_type(4))) float floatx4;
typedef unsigned long long u64;

__device__ __forceinline__ unsigned short f2bf(float f) {
    unsigned u = __float_as_uint(f);
    unsigned r = (u + 0x7fffu + ((u >> 16) & 1u)) >> 16;   // RNE
    return (unsigned short)r;
}

// ---------------------------------------------------------------------------
// fp32 -> bf16 flat convert (Q and K).
// ---------------------------------------------------------------------------
__global__ __launch_bounds__(256) void cvt_bf16(const float* __restrict__ src,
                                                unsigned short* __restrict__ dst, int n4) {
    int i = blockIdx.x * 256 + threadIdx.x;
    if (i < n4) {
        float4 v = ((const float4*)src)[i];
        ushort4 o;
        o.x = f2bf(v.x); o.y = f2bf(v.y); o.z = f2bf(v.z); o.w = f2bf(v.w);
        ((ushort4*)dst)[i] = o;
    }
}

// ---------------------------------------------------------------------------
// V[h][s][d] fp32 -> Vt[h][d][s] bf16 (64x64 LDS tile transpose).
// ---------------------------------------------------------------------------
__global__ __launch_bounds__(256) void transpose_v(const float* __restrict__ v,
                                                   unsigned short* __restrict__ vt) {
    int bx = blockIdx.x;
    int h  = bx >> 7;
    int rem = bx & 127;
    int d0 = (rem >> 6) * 64;
    int k0 = (rem & 63) * 64;
    __shared__ __align__(16) unsigned short T[64][72];
    int t = threadIdx.x;
#pragma unroll
    for (int it = 0; it < 4; ++it) {
        int idx = t + it * 256;
        int r = idx >> 4, c4 = idx & 15;
        float4 val = *(const float4*)(v + ((size_t)(h * S_LEN) + k0 + r) * DHEAD + d0 + c4 * 4);
        T[c4 * 4 + 0][r] = f2bf(val.x);
        T[c4 * 4 + 1][r] = f2bf(val.y);
        T[c4 * 4 + 2][r] = f2bf(val.z);
        T[c4 * 4 + 3][r] = f2bf(val.w);
    }
    __syncthreads();
#pragma unroll
    for (int it = 0; it < 2; ++it) {
        int idx = t + it * 256;
        int r = idx >> 3, c8 = idx & 7;
        *(uint4*)(vt + ((size_t)h * DHEAD + d0 + r) * S_LEN + k0 + c8 * 8) = *(uint4*)&T[r][c8 * 8];
    }
}

// ---------------------------------------------------------------------------
// P1: scores[h][qi][j] for last-64 queries, fp32 (keeps top-k faithful).
// 512 blocks x 256 threads; 4 lanes cooperate per key (32 dims each).
// ---------------------------------------------------------------------------
__global__ __launch_bounds__(256) void score_qk(const float* __restrict__ q,
                                                const float* __restrict__ k,
                                                float* __restrict__ scores) {
    int h  = blockIdx.x >> 6;
    int kt = blockIdx.x & 63;
    int t  = threadIdx.x;
    int jl = t >> 2, part = t & 3;
    int j  = kt * 64 + jl;

    __shared__ float4 Qs[64 * 32];
    const float4* qbase = (const float4*)(q + ((size_t)h * S_LEN + (S_LEN - LASTQ)) * DHEAD);
    for (int idx = t; idx < 64 * 32; idx += 256) Qs[idx] = qbase[idx];
    __syncthreads();

    float4 kr[8];
    const float4* kp = (const float4*)(k + ((size_t)h * S_LEN + j) * DHEAD) + part * 8;
#pragma unroll
    for (int c = 0; c < 8; ++c) kr[c] = kp[c];

    float* sp = scores + (size_t)h * LASTQ * S_LEN + j;
#pragma unroll 4
    for (int qi = 0; qi < LASTQ; ++qi) {
        const float4* qp4 = Qs + qi * 32 + part * 8;
        float dot = 0.f;
#pragma unroll
        for (int c = 0; c < 8; ++c) {
            float4 a = qp4[c], b = kr[c];
            dot += a.x * b.x + a.y * b.y + a.z * b.z + a.w * b.w;
        }
        dot += __shfl_xor(dot, 1, 64);
        dot += __shfl_xor(dot, 2, 64);
        if (part == 0) {
            int qpos = S_LEN - LASTQ + qi;
            sp[(size_t)qi * S_LEN] = (j <= qpos) ? dot * SCALE : NEGBIG;
        }
    }
}

// ---------------------------------------------------------------------------
// P2a: per-row softmax stats (m, 1/sum). 512 rows, one wave per row.
// ---------------------------------------------------------------------------
__global__ __launch_bounds__(256) void row_stats(const float* __restrict__ scores,
                                                 float* __restrict__ m_out,
                                                 float* __restrict__ inv_out) {
    int row  = blockIdx.x * 4 + (threadIdx.x >> 6);   // 128 blocks
    int lane = threadIdx.x & 63;
    const float4* rp = (const float4*)(scores + (size_t)row * S_LEN);
    float mx = NEGBIG;
    for (int i = lane; i < S_LEN / 4; i += 64) {
        float4 s4 = rp[i];
        mx = fmaxf(mx, fmaxf(fmaxf(s4.x, s4.y), fmaxf(s4.z, s4.w)));
    }
#pragma unroll
    for (int d = 32; d >= 1; d >>= 1) mx = fmaxf(mx, __shfl_xor(mx, d, 64));
    float su = 0.f;
    for (int i = lane; i < S_LEN / 4; i += 64) {
        float4 s4 = rp[i];
        su += __expf(s4.x - mx) + __expf(s4.y - mx) + __expf(s4.z - mx) + __expf(s4.w - mx);
    }
#pragma unroll
    for (int d = 32; d >= 1; d >>= 1) su += __shfl_xor(su, d, 64);
    if (lane == 0) { m_out[row] = mx; inv_out[row] = 1.0f / su; }
}

// ---------------------------------------------------------------------------
// P2b: vertical[j] and slash[o] directly (no atomics, coalesced gathers).
// 64 blocks x 256 threads.
// ---------------------------------------------------------------------------
__global__ __launch_bounds__(256) void vs_accum(const float* __restrict__ scores,
                                                const float* __restrict__ m_all,
                                                const float* __restrict__ inv_all,
                                                float* __restrict__ vertical,
                                                float* __restrict__ slash) {
    int h     = blockIdx.x >> 3;
    int chunk = blockIdx.x & 7;
    int t = threadIdx.x;
    __shared__ float sm[LASTQ], sv[LASTQ];
    if (t < LASTQ) { sm[t] = m_all[h * LASTQ + t]; sv[t] = inv_all[h * LASTQ + t]; }
    __syncthreads();

    const float* S0 = scores + (size_t)h * LASTQ * S_LEN;
#pragma unroll
    for (int rep = 0; rep < 2; ++rep) {
        int j = chunk * 512 + rep * 256 + t;
        float vacc = 0.f, sacc = 0.f;
        for (int r = 0; r < LASTQ; ++r) {
            vacc += __expf(S0[(size_t)r * S_LEN + j] - sm[r]) * sv[r];
            int idx = (S_LEN - LASTQ) + r - j;        // qpos_r - offset
            if (idx >= 0)
                sacc += __expf(S0[(size_t)r * S_LEN + idx] - sm[r]) * sv[r];
        }
        vertical[h * S_LEN + j] = vacc;
        slash[h * S_LEN + j]    = sacc;
    }
}

// ---------------------------------------------------------------------------
// Phase B: exact k-th-largest (radix select) -> membership bitmasks.
// ---------------------------------------------------------------------------
__global__ __launch_bounds__(256) void topk_mask(const float* __restrict__ vertical,
                                                 const float* __restrict__ slash,
                                                 unsigned* __restrict__ col_mask,
                                                 unsigned* __restrict__ diag_mask) {
    int h   = blockIdx.x >> 1;
    int sel = blockIdx.x & 1;
    const float* src = sel ? (slash + h * S_LEN) : (vertical + h * S_LEN);
    unsigned* dst    = sel ? (diag_mask + h * (S_LEN / 32)) : (col_mask + h * (S_LEN / 32));
    int kwant  = sel ? S_TOPK : V_TOPK;
    int forced = sel ? FORCE_S : FORCE_V;
    int t = threadIdx.x;

    __shared__ unsigned keys[S_LEN];
    __shared__ int hist[256];
    __shared__ int sh_digit, sh_want;

    for (int j = t; j < S_LEN; j += 256) {
        float f = (j < forced) ? __builtin_inff() : src[j];
        unsigned u = __float_as_uint(f);
        u = (u & 0x80000000u) ? ~u : (u | 0x80000000u);
        keys[j] = u;
    }
    __syncthreads();

    unsigned prefix = 0;
    int want = kwant;
    for (int shift = 24; shift >= 0; shift -= 8) {
        hist[t] = 0;
        __syncthreads();
        for (int j = t; j < S_LEN; j += 256) {
            unsigned key = keys[j];
            bool match = (shift == 24) || (((key ^ prefix) >> (shift + 8)) == 0);
            if (match) atomicAdd(&hist[(key >> shift) & 255u], 1);
        }
        __syncthreads();
        if (t == 0) {
            int cum = 0, d = 255;
            for (; d >= 0; --d) {
                cum += hist[d];
                if (cum >= want) break;
            }
            sh_digit = d;
            sh_want  = want - (cum - hist[d]);
        }
        __syncthreads();
        prefix |= ((unsigned)sh_digit) << shift;
        want = sh_want;
        __syncthreads();
    }
    for (int w = t; w < S_LEN / 32; w += 256) {
        unsigned bits = 0;
        for (int b = 0; b < 32; ++b)
            if (keys[w * 32 + b] >= prefix) bits |= (1u << b);
        dst[w] = bits;
    }
}

// ---------------------------------------------------------------------------
// Phase C: MFMA flash attention, split-K balanced jobs. Direct LDS staging
// (no long-lived register arrays — round 4's reg-prefetch spilled to scratch:
// WRITE_SIZE 16->464 MB; launch_bounds(256,2) keeps VGPR budget at 256).
// ---------------------------------------------------------------------------
#define KS_STRIDE 136
#define VT_STRIDE 72
#define PS_STRIDE 72

__global__ __launch_bounds__(256, 2) void sparse_attn_mfma(
        const unsigned short* __restrict__ qbf,
        const unsigned short* __restrict__ kbf,
        const unsigned short* __restrict__ vtbf,
        const unsigned* __restrict__ col_mask,
        const unsigned* __restrict__ diag_mask,
        float* __restrict__ pO, float* __restrict__ pm, float* __restrict__ pl) {
    int b = blockIdx.x;
    int h = b & 7;
    int j = b >> 3;          // 0..95, roughly descending work
    int qt, c0g, c1g, cidx;
    if (j < 64) {            // split jobs for qt in [32,63]
        qt = 63 - (j >> 1);
        int half = j & 1;
        int mid = (qt + 2) >> 1;
        cidx = half;
        c0g = half ? mid : 0;
        c1g = half ? (qt + 1) : mid;
    } else {                 // single jobs for qt in [0,31]
        qt = 95 - j;
        cidx = 0;
        c0g = 0;
        c1g = qt + 1;
    }
    int i0 = qt * 64;
    int t    = threadIdx.x;
    int wave = t >> 6;
    int lane = t & 63;
    int ln16 = lane & 15;
    int quad = lane >> 4;

    __shared__ __align__(16) unsigned short Ks[64 * KS_STRIDE];
    __shared__ __align__(16) unsigned short Vt[128 * VT_STRIDE];
    __shared__ __align__(16) unsigned short Ps[4 * 16 * PS_STRIDE];
    __shared__ u64 allowed[64];
    __shared__ unsigned dmLDS[130];

    if (t < 130) dmLDS[t] = (t < 128) ? diag_mask[h * 128 + t] : 0u;

    int qrow = i0 + wave * 16 + ln16;
    const unsigned short* qp = qbf + ((size_t)h * S_LEN + qrow) * DHEAD;
    short8 qf[4];
#pragma unroll
    for (int ds = 0; ds < 4; ++ds)
        qf[ds] = *(const short8*)(qp + ds * 32 + quad * 8);

    floatx4 o4[8];
#pragma unroll
    for (int n = 0; n < 8; ++n) o4[n] = (floatx4){0.f, 0.f, 0.f, 0.f};
    float m_run[4] = {NEGBIG, NEGBIG, NEGBIG, NEGBIG};
    float l_run[4] = {0.f, 0.f, 0.f, 0.f};

    unsigned short* psw = Ps + wave * 16 * PS_STRIDE;

    for (int jt = c0g; jt < c1g; ++jt) {
        int j0 = jt * 64;
        __syncthreads();   // previous tile's LDS reads done (covers dmLDS iter 0)

        // ---- stage K tile [64][128] + Vt tile [128][64] (transient regs) ----
#pragma unroll
        for (int it = 0; it < 4; ++it) {
            int idx = t + it * 256;
            int r = idx >> 4, c8 = idx & 15;
            *(uint4*)&Ks[r * KS_STRIDE + c8 * 8] =
                *(const uint4*)(kbf + ((size_t)(h * S_LEN) + j0 + r) * DHEAD + c8 * 8);
        }
#pragma unroll
        for (int it = 0; it < 4; ++it) {
            int idx = t + it * 256;
            int r = idx >> 3, c8 = idx & 7;
            *(uint4*)&Vt[r * VT_STRIDE + c8 * 8] =
                *(const uint4*)(vtbf + ((size_t)h * DHEAD + r) * S_LEN + j0 + c8 * 8);
        }
        if (t < 64) {
            int i = i0 + t;
            int off0 = i - j0;
            u64 causal = (off0 >= 63) ? ~0ull : ((1ull << (off0 + 1)) - 1ull);
            u64 cwv = ((u64)col_mask[h * 128 + (j0 >> 5) + 1] << 32) |
                      (u64)col_mask[h * 128 + (j0 >> 5)];
            int sb = off0 - 63;
            u64 V;
            if (sb >= 0) {
                int w = sb >> 5, sh = sb & 31;
                u64 lo = ((u64)dmLDS[w + 1] << 32) | (u64)dmLDS[w];
                u64 hi = (u64)dmLDS[w + 2];
                V = (lo >> sh) | (sh ? (hi << (64 - sh)) : 0ull);
            } else {
                u64 w0 = ((u64)dmLDS[1] << 32) | (u64)dmLDS[0];
                V = w0 << (-sb);
            }
            allowed[t] = (cwv | __brevll(V)) & causal;
        }
        __syncthreads();

        // ---- S = Q K^T ----
        floatx4 s_acc[4];
#pragma unroll
        for (int c = 0; c < 4; ++c) {
            s_acc[c] = (floatx4){0.f, 0.f, 0.f, 0.f};
            const unsigned short* kbase = Ks + (c * 16 + ln16) * KS_STRIDE + quad * 8;
#pragma unroll
            for (int ds = 0; ds < 4; ++ds) {
                short8 kf = *(const short8*)(kbase + ds * 32);
                s_acc[c] = __builtin_amdgcn_mfma_f32_16x16x32_bf16(qf[ds], kf, s_acc[c], 0, 0, 0);
            }
        }

        // ---- mask + scale ----
        u64 Arow[4];
#pragma unroll
        for (int r = 0; r < 4; ++r)
            Arow[r] = allowed[wave * 16 + quad * 4 + r];
        float sc[4][4];
#pragma unroll
        for (int c = 0; c < 4; ++c)
#pragma unroll
            for (int r = 0; r < 4; ++r) {
                bool ok = (Arow[r] >> (c * 16 + ln16)) & 1ull;
                sc[c][r] = ok ? s_acc[c][r] * SCALE : -__builtin_inff();
            }

        // ---- online softmax ----
        float mnew[4], alpha[4];
#pragma unroll
        for (int r = 0; r < 4; ++r) {
            float mx = fmaxf(fmaxf(sc[0][r], sc[1][r]), fmaxf(sc[2][r], sc[3][r]));
#pragma unroll
            for (int d = 8; d >= 1; d >>= 1) mx = fmaxf(mx, __shfl_xor(mx, d, 64));
            mnew[r] = fmaxf(m_run[r], mx);
            alpha[r] = __expf(m_run[r] - mnew[r]);
            m_run[r] = mnew[r];
        }
        float pv[4][4];
#pragma unroll
        for (int r = 0; r < 4; ++r) {
            float su = 0.f;
#pragma unroll
            for (int c = 0; c < 4; ++c) {
                float p = __expf(sc[c][r] - mnew[r]);
                pv[c][r] = p;
                su += p;
            }
#pragma unroll
            for (int d = 8; d >= 1; d >>= 1) su += __shfl_xor(su, d, 64);
            l_run[r] = l_run[r] * alpha[r] + su;
        }
#pragma unroll
        for (int n = 0; n < 8; ++n)
#pragma unroll
            for (int r = 0; r < 4; ++r) o4[n][r] *= alpha[r];

        // ---- P (C-layout) -> wave-private LDS -> A-layout ----
#pragma unroll
        for (int c = 0; c < 4; ++c)
#pragma unroll
            for (int r = 0; r < 4; ++r)
                psw[(quad * 4 + r) * PS_STRIDE + c * 16 + ln16] = f2bf(pv[c][r]);
        asm volatile("" ::: "memory");
        short8 pf0 = *(const short8*)&psw[ln16 * PS_STRIDE + quad * 8];
        short8 pf1 = *(const short8*)&psw[ln16 * PS_STRIDE + 32 + quad * 8];

        // ---- O += P V ----
#pragma unroll
        for (int n = 0; n < 8; ++n) {
            const unsigned short* vbase = Vt + (n * 16 + ln16) * VT_STRIDE + quad * 8;
            short8 vf0 = *(const short8*)(vbase);
            short8 vf1 = *(const short8*)(vbase + 32);
            o4[n] = __builtin_amdgcn_mfma_f32_16x16x32_bf16(pf0, vf0, o4[n], 0, 0, 0);
            o4[n] = __builtin_amdgcn_mfma_f32_16x16x32_bf16(pf1, vf1, o4[n], 0, 0, 0);
        }
    }

    // ---- write partial (O, m, l) ----
    int pi = (h * 64 + qt) * 2 + cidx;
    float* pOp = pO + (size_t)pi * (64 * DHEAD);
#pragma unroll
    for (int r = 0; r < 4; ++r) {
        int row = wave * 16 + quad * 4 + r;
        if (ln16 == 0) { pm[pi * 64 + row] = m_run[r]; pl[pi * 64 + row] = l_run[r]; }
#pragma unroll
        for (int n = 0; n < 8; ++n)
            pOp[row * DHEAD + n * 16 + ln16] = o4[n][r];
    }
}

// ---------------------------------------------------------------------------
// Merge partials -> normalized output. 512 blocks x 256 threads.
// ---------------------------------------------------------------------------
__global__ __launch_bounds__(256) void merge_out(const float* __restrict__ pO,
                                                 const float* __restrict__ pm,
                                                 const float* __restrict__ pl,
                                                 float* __restrict__ out) {
    int b = blockIdx.x;
    int qt = b & 63;
    int t = threadIdx.x;
    int row = t >> 2, cg = t & 3;
    int pi0 = b * 2;
    bool two = (qt >= 32);

    float m0 = pm[pi0 * 64 + row], l0 = pl[pi0 * 64 + row];
    float w0 = 1.f, w1 = 0.f, denom = l0;
    if (two) {
        float m1 = pm[(pi0 + 1) * 64 + row], l1 = pl[(pi0 + 1) * 64 + row];
        float ms = fmaxf(m0, m1);
        w0 = __expf(m0 - ms);
        w1 = __expf(m1 - ms);
        denom = w0 * l0 + w1 * l1;
    }
    float invl = 1.0f / denom;

    const float4* O0 = (const float4*)(pO + (size_t)pi0 * (64 * DHEAD) + row * DHEAD + cg * 32);
    const float4* O1 = (const float4*)((const float*)O0 + 64 * DHEAD);
    float4* op = (float4*)(out + ((size_t)b * 64 + row) * DHEAD + cg * 32);
#pragma unroll
    for (int i = 0; i < 8; ++i) {
        float4 a = O0[i];
        float4 c;
        if (two) {
            float4 bb = O1[i];
            c.x = (w0 * a.x + w1 * bb.x) * invl;
            c.y = (w0 * a.y + w1 * bb.y) * invl;
            c.z = (w0 * a.z + w1 * bb.z) * invl;
            c.w = (w0 * a.w + w1 * bb.w) * invl;
        } else {
            c.x = a.x * invl; c.y = a.y * invl; c.z = a.z * invl; c.w = a.w * invl;
        }
        op[i] = c;
    }
}

// ---------------------------------------------------------------------------
extern "C" void kernel_launch(void* const* d_in, const int* in_sizes, int n_in,
                              void* d_out, int out_size, void* d_ws, size_t ws_size,
                              hipStream_t stream) {
    const float* q = (const float*)d_in[0];
    const float* k = (const float*)d_in[1];
    const float* v = (const float*)d_in[2];
    float* out = (float*)d_out;

    float* vertical = (float*)d_ws;                              // 32768 f32
    float* slash    = vertical + NHEAD * S_LEN;                  // 32768 f32
    unsigned* col_m  = (unsigned*)(slash + NHEAD * S_LEN);       // 1024 u32
    unsigned* diag_m = col_m + NHEAD * (S_LEN / 32);             // 1024 u32
    float* m_all   = (float*)(diag_m + NHEAD * (S_LEN / 32));    // 512 f32
    float* inv_all = m_all + NHEAD * LASTQ;                      // 512 f32
    unsigned short* qbf  = (unsigned short*)(inv_all + NHEAD * LASTQ);
    unsigned short* kbf  = qbf + (size_t)NHEAD * S_LEN * DHEAD;
    unsigned short* vtbf = kbf + (size_t)NHEAD * S_LEN * DHEAD;
    // big region: scores (8 MB) during pattern phase, pO (32 MB) during attention
    float* big = (float*)(vtbf + (size_t)NHEAD * S_LEN * DHEAD);
    float* scores = big;
    float* pO = big;
    float* pm = big + (size_t)1024 * 64 * DHEAD;
    float* pl = pm + 1024 * 64;

    int n4 = NHEAD * S_LEN * DHEAD / 4;
    cvt_bf16<<<(n4 + 255) / 256, 256, 0, stream>>>(q, qbf, n4);
    cvt_bf16<<<(n4 + 255) / 256, 256, 0, stream>>>(k, kbf, n4);
    transpose_v<<<NHEAD * 2 * (S_LEN / 64), 256, 0, stream>>>(v, vtbf);

    score_qk<<<NHEAD * 64, 256, 0, stream>>>(q, k, scores);
    row_stats<<<NHEAD * LASTQ / 4, 256, 0, stream>>>(scores, m_all, inv_all);
    vs_accum<<<NHEAD * 8, 256, 0, stream>>>(scores, m_all, inv_all, vertical, slash);
    topk_mask<<<NHEAD * 2, 256, 0, stream>>>(vertical, slash, col_m, diag_m);

    sparse_attn_mfma<<<NHEAD * 96, 256, 0, stream>>>(qbf, kbf, vtbf, col_m, diag_m, pO, pm, pl);
    merge_out<<<NHEAD * 64, 256, 0, stream>>>(pO, pm, pl, out);
}

// Round 6
// 300.922 us; speedup vs baseline: 2.6660x; 1.2037x over previous
//
#include <hip/hip_runtime.h>
#include <hip/hip_bf16.h>
#include <math.h>

#define S_LEN 4096
#define DHEAD 128
#define NHEAD 8
#define LASTQ 64
#define V_TOPK 1024
#define S_TOPK 2048
#define FORCE_V 30
#define FORCE_S 100

#define SCALE 0.08838834764831845f
#define NEGBIG -3.0e38f

#define NJOBS 111   // split-K jobs per head (chunks of <=11 k-tiles)

typedef __attribute__((ext_vector_type(8))) short short8;
typedef __attribute__((ext_vector_type(4))) float floatx4;
typedef unsigned long long u64;

__device__ __forceinline__ unsigned short f2bf(float f) {
    unsigned u = __float_as_uint(f);
    unsigned r = (u + 0x7fffu + ((u >> 16) & 1u)) >> 16;   // RNE
    return (unsigned short)r;
}
__device__ __forceinline__ float bf2f(unsigned short s) {
    unsigned u = ((unsigned)s) << 16;
    return __uint_as_float(u);
}

// ---- split-K job tables: per head, q-block Q in [0,32) (128 rows each),
// k-range [K0,K1) in 64-key tiles; job id == partial index. ----
__device__ const short jobQ[NJOBS] = {
    0,1,2,3,4, 5,5, 6,6, 7,7, 8,8, 9,9, 10,10,
    11,11,11, 12,12,12, 13,13,13, 14,14,14, 15,15,15,
    16,16,16,16, 17,17,17,17, 18,18,18,18, 19,19,19,19, 20,20,20,20, 21,21,21,21,
    22,22,22,22,22, 23,23,23,23,23, 24,24,24,24,24, 25,25,25,25,25, 26,26,26,26,26,
    27,27,27,27,27,27, 28,28,28,28,28,28, 29,29,29,29,29,29, 30,30,30,30,30,30,
    31,31,31,31,31,31};
__device__ const short jobK0[NJOBS] = {
    0,0,0,0,0, 0,6, 0,7, 0,8, 0,9, 0,10, 0,11,
    0,8,16, 0,9,18, 0,10,19, 0,10,20, 0,11,22,
    0,9,18,26, 0,9,18,27, 0,10,20,29, 0,10,20,30, 0,11,22,32, 0,11,22,33,
    0,10,19,28,37, 0,10,20,30,39, 0,10,20,30,40, 0,11,22,32,42, 0,11,22,33,44,
    0,10,20,29,38,47, 0,10,20,30,40,49, 0,10,20,30,40,50, 0,11,22,32,42,52,
    0,11,22,33,44,54};
__device__ const short jobK1[NJOBS] = {
    2,4,6,8,10, 6,12, 7,14, 8,16, 9,18, 10,20, 11,22,
    8,16,24, 9,18,26, 10,19,28, 10,20,30, 11,22,32,
    9,18,26,34, 9,18,27,36, 10,20,29,38, 10,20,30,40, 11,22,32,42, 11,22,33,44,
    10,19,28,37,46, 10,20,30,39,48, 10,20,30,40,50, 11,22,32,42,52, 11,22,33,44,54,
    10,20,29,38,47,56, 10,20,30,40,49,58, 10,20,30,40,50,60, 11,22,32,42,52,62,
    11,22,33,44,54,64};
__device__ const short pBase[32] = {0,1,2,3,4,5,7,9,11,13,15,17,20,23,26,29,
                                    32,36,40,44,48,52,56,61,66,71,76,81,87,93,99,105};
__device__ const short pCnt[32]  = {1,1,1,1,1,2,2,2,2,2,2,3,3,3,3,3,
                                    4,4,4,4,4,4,5,5,5,5,5,6,6,6,6,6};

// ---------------------------------------------------------------------------
// Prep: K fp32->bf16 (blocks 0..511) + V transpose to Vt[h][d][s] bf16
// (blocks 512..1535). One launch.
// ---------------------------------------------------------------------------
__global__ __launch_bounds__(256) void prep(const float* __restrict__ k,
                                            const float* __restrict__ v,
                                            unsigned short* __restrict__ kbf,
                                            unsigned short* __restrict__ vtbf) {
    int b = blockIdx.x, t = threadIdx.x;
    if (b < 512) {
        const float4* src = (const float4*)k;
        int base = b * 2048;
#pragma unroll
        for (int i = 0; i < 8; ++i) {
            int idx = base + i * 256 + t;
            float4 val = src[idx];
            ushort4 o;
            o.x = f2bf(val.x); o.y = f2bf(val.y); o.z = f2bf(val.z); o.w = f2bf(val.w);
            ((ushort4*)kbf)[idx] = o;
        }
    } else {
        int bx = b - 512;
        int h  = bx >> 7;
        int rem = bx & 127;
        int d0 = (rem >> 6) * 64;
        int k0 = (rem & 63) * 64;
        __shared__ __align__(16) unsigned short T[64][72];
#pragma unroll
        for (int it = 0; it < 4; ++it) {
            int idx = t + it * 256;
            int r = idx >> 4, c4 = idx & 15;
            float4 val = *(const float4*)(v + ((size_t)(h * S_LEN) + k0 + r) * DHEAD + d0 + c4 * 4);
            T[c4 * 4 + 0][r] = f2bf(val.x);
            T[c4 * 4 + 1][r] = f2bf(val.y);
            T[c4 * 4 + 2][r] = f2bf(val.z);
            T[c4 * 4 + 3][r] = f2bf(val.w);
        }
        __syncthreads();
#pragma unroll
        for (int it = 0; it < 2; ++it) {
            int idx = t + it * 256;
            int r = idx >> 3, c8 = idx & 7;
            *(uint4*)(vtbf + ((size_t)h * DHEAD + d0 + r) * S_LEN + k0 + c8 * 8) = *(uint4*)&T[r][c8 * 8];
        }
    }
}

// ---------------------------------------------------------------------------
// P1: scores[h][qi][j] for last-64 queries, fp32 (keeps top-k faithful).
// ---------------------------------------------------------------------------
__global__ __launch_bounds__(256) void score_qk(const float* __restrict__ q,
                                                const float* __restrict__ k,
                                                float* __restrict__ scores) {
    int h  = blockIdx.x >> 6;
    int kt = blockIdx.x & 63;
    int t  = threadIdx.x;
    int jl = t >> 2, part = t & 3;
    int j  = kt * 64 + jl;

    __shared__ float4 Qs[64 * 32];
    const float4* qbase = (const float4*)(q + ((size_t)h * S_LEN + (S_LEN - LASTQ)) * DHEAD);
    for (int idx = t; idx < 64 * 32; idx += 256) Qs[idx] = qbase[idx];
    __syncthreads();

    float4 kr[8];
    const float4* kp = (const float4*)(k + ((size_t)h * S_LEN + j) * DHEAD) + part * 8;
#pragma unroll
    for (int c = 0; c < 8; ++c) kr[c] = kp[c];

    float* sp = scores + (size_t)h * LASTQ * S_LEN + j;
#pragma unroll 4
    for (int qi = 0; qi < LASTQ; ++qi) {
        const float4* qp4 = Qs + qi * 32 + part * 8;
        float dot = 0.f;
#pragma unroll
        for (int c = 0; c < 8; ++c) {
            float4 a = qp4[c], b = kr[c];
            dot += a.x * b.x + a.y * b.y + a.z * b.z + a.w * b.w;
        }
        dot += __shfl_xor(dot, 1, 64);
        dot += __shfl_xor(dot, 2, 64);
        if (part == 0) {
            int qpos = S_LEN - LASTQ + qi;
            sp[(size_t)qi * S_LEN] = (j <= qpos) ? dot * SCALE : NEGBIG;
        }
    }
}

// ---------------------------------------------------------------------------
// P2a: per-row softmax stats (m, 1/sum). 512 rows, one wave per row.
// ---------------------------------------------------------------------------
__global__ __launch_bounds__(256) void row_stats(const float* __restrict__ scores,
                                                 float* __restrict__ m_out,
                                                 float* __restrict__ inv_out) {
    int row  = blockIdx.x * 4 + (threadIdx.x >> 6);
    int lane = threadIdx.x & 63;
    const float4* rp = (const float4*)(scores + (size_t)row * S_LEN);
    float mx = NEGBIG;
    for (int i = lane; i < S_LEN / 4; i += 64) {
        float4 s4 = rp[i];
        mx = fmaxf(mx, fmaxf(fmaxf(s4.x, s4.y), fmaxf(s4.z, s4.w)));
    }
#pragma unroll
    for (int d = 32; d >= 1; d >>= 1) mx = fmaxf(mx, __shfl_xor(mx, d, 64));
    float su = 0.f;
    for (int i = lane; i < S_LEN / 4; i += 64) {
        float4 s4 = rp[i];
        su += __expf(s4.x - mx) + __expf(s4.y - mx) + __expf(s4.z - mx) + __expf(s4.w - mx);
    }
#pragma unroll
    for (int d = 32; d >= 1; d >>= 1) su += __shfl_xor(su, d, 64);
    if (lane == 0) { m_out[row] = mx; inv_out[row] = 1.0f / su; }
}

// ---------------------------------------------------------------------------
// P2b+B fused: per (head, {vertical,slash}) accumulate scores + exact
// k-th-largest radix select -> membership bitmask. 16 blocks x 1024 threads.
// ---------------------------------------------------------------------------
__global__ __launch_bounds__(1024) void pattern_finish(const float* __restrict__ scores,
                                                       const float* __restrict__ m_all,
                                                       const float* __restrict__ inv_all,
                                                       unsigned* __restrict__ col_mask,
                                                       unsigned* __restrict__ diag_mask) {
    int h   = blockIdx.x >> 1;
    int sel = blockIdx.x & 1;
    int t = threadIdx.x;
    int kwant  = sel ? S_TOPK : V_TOPK;
    int forced = sel ? FORCE_S : FORCE_V;
    unsigned* dst = sel ? (diag_mask + h * 128) : (col_mask + h * 128);

    __shared__ float sm[LASTQ], sv[LASTQ];
    __shared__ unsigned keys[S_LEN];
    __shared__ int hist[256];
    __shared__ int sh_digit, sh_want;

    if (t < LASTQ) { sm[t] = m_all[h * LASTQ + t]; sv[t] = inv_all[h * LASTQ + t]; }
    __syncthreads();

    const float* S0 = scores + (size_t)h * LASTQ * S_LEN;
#pragma unroll
    for (int rep = 0; rep < 4; ++rep) {
        int j = rep * 1024 + t;
        float acc = 0.f;
        if (sel == 0) {
            for (int r = 0; r < LASTQ; ++r)
                acc += __expf(S0[(size_t)r * S_LEN + j] - sm[r]) * sv[r];
        } else {
            for (int r = 0; r < LASTQ; ++r) {
                int idx = (S_LEN - LASTQ) + r - j;
                if (idx >= 0)
                    acc += __expf(S0[(size_t)r * S_LEN + idx] - sm[r]) * sv[r];
            }
        }
        float f = (j < forced) ? __builtin_inff() : acc;
        unsigned u = __float_as_uint(f);
        u = (u & 0x80000000u) ? ~u : (u | 0x80000000u);
        keys[j] = u;
    }
    __syncthreads();

    unsigned prefix = 0;
    int want = kwant;
    for (int shift = 24; shift >= 0; shift -= 8) {
        if (t < 256) hist[t] = 0;
        __syncthreads();
        for (int j = t; j < S_LEN; j += 1024) {
            unsigned key = keys[j];
            bool match = (shift == 24) || (((key ^ prefix) >> (shift + 8)) == 0);
            if (match) atomicAdd(&hist[(key >> shift) & 255u], 1);
        }
        __syncthreads();
        if (t == 0) {
            int cum = 0, d = 255;
            for (; d >= 0; --d) {
                cum += hist[d];
                if (cum >= want) break;
            }
            sh_digit = d;
            sh_want  = want - (cum - hist[d]);
        }
        __syncthreads();
        prefix |= ((unsigned)sh_digit) << shift;
        want = sh_want;
        __syncthreads();
    }
    if (t < 128) {
        unsigned bits = 0;
        for (int b = 0; b < 32; ++b)
            if (keys[t * 32 + b] >= prefix) bits |= (1u << b);
        dst[t] = bits;
    }
}

// ---------------------------------------------------------------------------
// Phase C: MFMA flash attention, 128 q-rows per block (two 16-row subtiles
// per wave share every K/V LDS fragment read), split-K jobs, bf16 partials.
// ---------------------------------------------------------------------------
#define KS_STRIDE 136
#define VT_STRIDE 72
#define PS_STRIDE 72

__global__ __launch_bounds__(256, 2) void sparse_attn_mfma(
        const float* __restrict__ q,
        const unsigned short* __restrict__ kbf,
        const unsigned short* __restrict__ vtbf,
        const unsigned* __restrict__ col_mask,
        const unsigned* __restrict__ diag_mask,
        unsigned short* __restrict__ pO, float* __restrict__ pm, float* __restrict__ pl) {
    int b = blockIdx.x;
    int h = b & 7;
    int job = b >> 3;                 // 0..110
    int Q  = jobQ[job];
    int k0 = jobK0[job];
    int k1 = jobK1[job];
    int i0 = Q * 128;
    int t    = threadIdx.x;
    int wave = t >> 6;
    int lane = t & 63;
    int ln16 = lane & 15;
    int quad = lane >> 4;

    __shared__ __align__(16) unsigned short Ks[64 * KS_STRIDE];
    __shared__ __align__(16) unsigned short Vt[128 * VT_STRIDE];
    __shared__ __align__(16) unsigned short Ps[8 * 16 * PS_STRIDE];
    __shared__ u64 allowed[128];
    __shared__ unsigned dmLDS[130];

    if (t < 130) dmLDS[t] = (t < 128) ? diag_mask[h * 128 + t] : 0u;

    // Q fragments for both 16-row subtiles (SCALE folded in), fp32 -> bf16
    short8 qf[2][4];
#pragma unroll
    for (int s = 0; s < 2; ++s) {
        int qrow = i0 + wave * 32 + s * 16 + ln16;
        const float* qp = q + ((size_t)h * S_LEN + qrow) * DHEAD;
#pragma unroll
        for (int ds = 0; ds < 4; ++ds) {
            int base = ds * 32 + quad * 8;
            float4 a = *(const float4*)(qp + base);
            float4 c = *(const float4*)(qp + base + 4);
            union { unsigned short u[8]; short8 v; } tmp;
            tmp.u[0] = f2bf(a.x * SCALE); tmp.u[1] = f2bf(a.y * SCALE);
            tmp.u[2] = f2bf(a.z * SCALE); tmp.u[3] = f2bf(a.w * SCALE);
            tmp.u[4] = f2bf(c.x * SCALE); tmp.u[5] = f2bf(c.y * SCALE);
            tmp.u[6] = f2bf(c.z * SCALE); tmp.u[7] = f2bf(c.w * SCALE);
            qf[s][ds] = tmp.v;
        }
    }

    floatx4 o4[2][8];
#pragma unroll
    for (int s = 0; s < 2; ++s)
#pragma unroll
        for (int n = 0; n < 8; ++n) o4[s][n] = (floatx4){0.f, 0.f, 0.f, 0.f};
    float m_run[2][4] = {{NEGBIG, NEGBIG, NEGBIG, NEGBIG}, {NEGBIG, NEGBIG, NEGBIG, NEGBIG}};
    float l_run[2][4] = {{0.f, 0.f, 0.f, 0.f}, {0.f, 0.f, 0.f, 0.f}};

    unsigned short* psw[2];
    psw[0] = Ps + (wave * 2 + 0) * 16 * PS_STRIDE;
    psw[1] = Ps + (wave * 2 + 1) * 16 * PS_STRIDE;

    for (int jt = k0; jt < k1; ++jt) {
        int j0 = jt * 64;
        __syncthreads();   // previous iteration's LDS reads done

        // ---- stage K tile [64][128] + Vt tile [128][64] ----
#pragma unroll
        for (int it = 0; it < 4; ++it) {
            int idx = t + it * 256;
            int r = idx >> 4, c8 = idx & 15;
            *(uint4*)&Ks[r * KS_STRIDE + c8 * 8] =
                *(const uint4*)(kbf + ((size_t)(h * S_LEN) + j0 + r) * DHEAD + c8 * 8);
        }
#pragma unroll
        for (int it = 0; it < 4; ++it) {
            int idx = t + it * 256;
            int r = idx >> 3, c8 = idx & 7;
            *(uint4*)&Vt[r * VT_STRIDE + c8 * 8] =
                *(const uint4*)(vtbf + ((size_t)h * DHEAD + r) * S_LEN + j0 + c8 * 8);
        }
        // ---- per-row allowed bitmask (128 rows) ----
        if (t < 128) {
            int i = i0 + t;
            int off0 = i - j0;
            u64 a = 0;
            if (off0 >= 0) {
                u64 causal = (off0 >= 63) ? ~0ull : ((1ull << (off0 + 1)) - 1ull);
                u64 cwv = ((u64)col_mask[h * 128 + (j0 >> 5) + 1] << 32) |
                          (u64)col_mask[h * 128 + (j0 >> 5)];
                int sb = off0 - 63;
                u64 V;
                if (sb >= 0) {
                    int w = sb >> 5, sh = sb & 31;
                    u64 lo = ((u64)dmLDS[w + 1] << 32) | (u64)dmLDS[w];
                    u64 hi = (u64)dmLDS[w + 2];
                    V = (lo >> sh) | (sh ? (hi << (64 - sh)) : 0ull);
                } else {
                    u64 w0 = ((u64)dmLDS[1] << 32) | (u64)dmLDS[0];
                    V = w0 << (-sb);
                }
                a = (cwv | __brevll(V)) & causal;
            }
            allowed[t] = a;
        }
        __syncthreads();

        // ---- S = Q K^T, both subtiles share each K fragment ----
        floatx4 sa[2][4];
#pragma unroll
        for (int s = 0; s < 2; ++s)
#pragma unroll
            for (int c = 0; c < 4; ++c) sa[s][c] = (floatx4){0.f, 0.f, 0.f, 0.f};
#pragma unroll
        for (int c = 0; c < 4; ++c) {
            const unsigned short* kbase = Ks + (c * 16 + ln16) * KS_STRIDE + quad * 8;
#pragma unroll
            for (int ds = 0; ds < 4; ++ds) {
                short8 kf = *(const short8*)(kbase + ds * 32);
                sa[0][c] = __builtin_amdgcn_mfma_f32_16x16x32_bf16(qf[0][ds], kf, sa[0][c], 0, 0, 0);
                sa[1][c] = __builtin_amdgcn_mfma_f32_16x16x32_bf16(qf[1][ds], kf, sa[1][c], 0, 0, 0);
            }
        }

        // ---- mask + online softmax + P->LDS, per subtile ----
#pragma unroll
        for (int s = 0; s < 2; ++s) {
            u64 Arow[4];
#pragma unroll
            for (int r = 0; r < 4; ++r)
                Arow[r] = allowed[wave * 32 + s * 16 + quad * 4 + r];
            float sc[4][4];
#pragma unroll
            for (int c = 0; c < 4; ++c)
#pragma unroll
                for (int r = 0; r < 4; ++r) {
                    bool ok = (Arow[r] >> (c * 16 + ln16)) & 1ull;
                    sc[c][r] = ok ? sa[s][c][r] : -__builtin_inff();
                }
            float mnew[4], alpha[4];
#pragma unroll
            for (int r = 0; r < 4; ++r) {
                float mx = fmaxf(fmaxf(sc[0][r], sc[1][r]), fmaxf(sc[2][r], sc[3][r]));
#pragma unroll
                for (int d = 8; d >= 1; d >>= 1) mx = fmaxf(mx, __shfl_xor(mx, d, 64));
                mnew[r] = fmaxf(m_run[s][r], mx);
                alpha[r] = __expf(m_run[s][r] - mnew[r]);
                m_run[s][r] = mnew[r];
            }
#pragma unroll
            for (int r = 0; r < 4; ++r) {
                float su = 0.f;
                float pvr[4];
#pragma unroll
                for (int c = 0; c < 4; ++c) {
                    float p = __expf(sc[c][r] - mnew[r]);
                    pvr[c] = p;
                    su += p;
                }
#pragma unroll
                for (int c = 0; c < 4; ++c)
                    psw[s][(quad * 4 + r) * PS_STRIDE + c * 16 + ln16] = f2bf(pvr[c]);
#pragma unroll
                for (int d = 8; d >= 1; d >>= 1) su += __shfl_xor(su, d, 64);
                l_run[s][r] = l_run[s][r] * alpha[r] + su;
            }
#pragma unroll
            for (int n = 0; n < 8; ++n)
#pragma unroll
                for (int r = 0; r < 4; ++r) o4[s][n][r] *= alpha[r];
        }
        asm volatile("" ::: "memory");   // order psw writes before reads (per-wave DS in-order)

        short8 pf[2][2];
#pragma unroll
        for (int s = 0; s < 2; ++s) {
            pf[s][0] = *(const short8*)&psw[s][ln16 * PS_STRIDE + quad * 8];
            pf[s][1] = *(const short8*)&psw[s][ln16 * PS_STRIDE + 32 + quad * 8];
        }

        // ---- O += P V, both subtiles share each V fragment ----
#pragma unroll
        for (int n = 0; n < 8; ++n) {
            const unsigned short* vbase = Vt + (n * 16 + ln16) * VT_STRIDE + quad * 8;
            short8 vf0 = *(const short8*)(vbase);
            short8 vf1 = *(const short8*)(vbase + 32);
            o4[0][n] = __builtin_amdgcn_mfma_f32_16x16x32_bf16(pf[0][0], vf0, o4[0][n], 0, 0, 0);
            o4[0][n] = __builtin_amdgcn_mfma_f32_16x16x32_bf16(pf[0][1], vf1, o4[0][n], 0, 0, 0);
            o4[1][n] = __builtin_amdgcn_mfma_f32_16x16x32_bf16(pf[1][0], vf0, o4[1][n], 0, 0, 0);
            o4[1][n] = __builtin_amdgcn_mfma_f32_16x16x32_bf16(pf[1][1], vf1, o4[1][n], 0, 0, 0);
        }
    }

    // ---- write partial (O bf16, m, l) ----
    int pidx = h * NJOBS + job;
    unsigned short* pOp = pO + (size_t)pidx * (128 * DHEAD);
#pragma unroll
    for (int s = 0; s < 2; ++s)
#pragma unroll
        for (int r = 0; r < 4; ++r) {
            int row = wave * 32 + s * 16 + quad * 4 + r;
            if (ln16 == 0) {
                pm[pidx * 128 + row] = m_run[s][r];
                pl[pidx * 128 + row] = l_run[s][r];
            }
#pragma unroll
            for (int n = 0; n < 8; ++n)
                pOp[row * DHEAD + n * 16 + ln16] = f2bf(o4[s][n][r]);
        }
}

// ---------------------------------------------------------------------------
// Merge partials -> normalized output. 256 blocks (h,Q) x 256 threads.
// ---------------------------------------------------------------------------
__global__ __launch_bounds__(256) void merge_out(const unsigned short* __restrict__ pO,
                                                 const float* __restrict__ pm,
                                                 const float* __restrict__ pl,
                                                 float* __restrict__ out) {
    int b = blockIdx.x;
    int h = b >> 5, Q = b & 31;
    int t = threadIdx.x;
    int row = t >> 1, half = t & 1;
    int p0 = h * NJOBS + pBase[Q];
    int cnt = pCnt[Q];

    float mp[6], lp[6];
    float ms = NEGBIG;
    for (int p = 0; p < cnt; ++p) {
        mp[p] = pm[(p0 + p) * 128 + row];
        lp[p] = pl[(p0 + p) * 128 + row];
        ms = fmaxf(ms, mp[p]);
    }
    float denom = 0.f, w[6];
    for (int p = 0; p < cnt; ++p) {
        w[p] = __expf(mp[p] - ms);
        denom += w[p] * lp[p];
    }
    float invl = 1.0f / denom;

    float acc[64];
#pragma unroll
    for (int i = 0; i < 64; ++i) acc[i] = 0.f;
    for (int p = 0; p < cnt; ++p) {
        const unsigned short* Op = pO + (size_t)(p0 + p) * (128 * DHEAD) + row * DHEAD + half * 64;
        float wp = w[p];
#pragma unroll
        for (int g = 0; g < 8; ++g) {
            ushort4 u0 = ((const ushort4*)Op)[g * 2];
            ushort4 u1 = ((const ushort4*)Op)[g * 2 + 1];
            acc[g * 8 + 0] += wp * bf2f(u0.x); acc[g * 8 + 1] += wp * bf2f(u0.y);
            acc[g * 8 + 2] += wp * bf2f(u0.z); acc[g * 8 + 3] += wp * bf2f(u0.w);
            acc[g * 8 + 4] += wp * bf2f(u1.x); acc[g * 8 + 5] += wp * bf2f(u1.y);
            acc[g * 8 + 6] += wp * bf2f(u1.z); acc[g * 8 + 7] += wp * bf2f(u1.w);
        }
    }
    float* op = out + ((size_t)h * S_LEN + Q * 128 + row) * DHEAD + half * 64;
#pragma unroll
    for (int g = 0; g < 16; ++g) {
        float4 c;
        c.x = acc[g * 4 + 0] * invl; c.y = acc[g * 4 + 1] * invl;
        c.z = acc[g * 4 + 2] * invl; c.w = acc[g * 4 + 3] * invl;
        ((float4*)op)[g] = c;
    }
}

// ---------------------------------------------------------------------------
extern "C" void kernel_launch(void* const* d_in, const int* in_sizes, int n_in,
                              void* d_out, int out_size, void* d_ws, size_t ws_size,
                              hipStream_t stream) {
    const float* q = (const float*)d_in[0];
    const float* k = (const float*)d_in[1];
    const float* v = (const float*)d_in[2];
    float* out = (float*)d_out;

    unsigned* col_m  = (unsigned*)d_ws;                          // 1024 u32
    unsigned* diag_m = col_m + 1024;                             // 1024 u32
    float* m_all   = (float*)(diag_m + 1024);                    // 512 f32
    float* inv_all = m_all + 512;                                // 512 f32
    unsigned short* kbf  = (unsigned short*)(inv_all + 512);     // 4M bf16 (8 MB)
    unsigned short* vtbf = kbf + (size_t)NHEAD * S_LEN * DHEAD;  // 4M bf16 (8 MB)
    float* scores = (float*)(vtbf + (size_t)NHEAD * S_LEN * DHEAD);          // 8 MB
    unsigned short* pO = (unsigned short*)(scores + (size_t)NHEAD * LASTQ * S_LEN); // 29.1 MB
    float* pm = (float*)(pO + (size_t)8 * NJOBS * 128 * DHEAD);  // 888*128 f32
    float* pl = pm + 8 * NJOBS * 128;

    prep<<<1536, 256, 0, stream>>>(k, v, kbf, vtbf);
    score_qk<<<NHEAD * 64, 256, 0, stream>>>(q, k, scores);
    row_stats<<<NHEAD * LASTQ / 4, 256, 0, stream>>>(scores, m_all, inv_all);
    pattern_finish<<<NHEAD * 2, 1024, 0, stream>>>(scores, m_all, inv_all, col_m, diag_m);
    sparse_attn_mfma<<<NHEAD * NJOBS, 256, 0, stream>>>(q, kbf, vtbf, col_m, diag_m, pO, pm, pl);
    merge_out<<<NHEAD * 32, 256, 0, stream>>>(pO, pm, pl, out);
}